// Round 1
// baseline (208.002 us; speedup 1.0000x reference)
//
#include <hip/hip_runtime.h>
#include <hip/hip_bf16.h>

typedef __attribute__((ext_vector_type(8))) short short8;
typedef __attribute__((ext_vector_type(4))) float f32x4;

#define LN_EPS 1e-5f

__device__ __forceinline__ unsigned short f2bf(float f) {
  union { float f; unsigned u; } v; v.f = f;
  unsigned r = v.u + 0x7FFFu + ((v.u >> 16) & 1u);
  return (unsigned short)(r >> 16);
}

// x: (2, 96, 32, 128, 128) f32
// w: (192, 768) f32, gamma/beta: (768,) f32
// out: (2, 192, 16, 64, 64) f32
//
// k-permutation: k' = (dd*2+hh)*192 + c*2 + ww   (orig k = (dd*2+hh)*192 + ww*96 + c)
// Weights pre-swizzled to MFMA B-frag order: [NT(12)][ks(24)][lane(64)][8 bf16]

__global__ __launch_bounds__(256) void pm_prep(
    const float* __restrict__ w, const float* __restrict__ g,
    const float* __restrict__ be, unsigned short* __restrict__ wg,
    float* __restrict__ sb) {
  const int o = blockIdx.x;   // 0..191
  const int t = threadIdx.x;  // 0..255
  __shared__ float red[256][2];
  float sa = 0.f, ba = 0.f;
#pragma unroll
  for (int u = 0; u < 3; ++u) {
    int kp = t + 256 * u;             // k' in 0..767
    int dh = kp / 192;
    int rem = kp - dh * 192;
    int c = rem >> 1, ww = rem & 1;
    int k = dh * 192 + ww * 96 + c;   // original k
    float wv = w[o * 768 + k];
    float v = wv * g[k];
    sa += v;
    ba += wv * be[k];
    int NT = o >> 4, ks = kp >> 5, q = (kp >> 3) & 3, jj = kp & 7;
    wg[(((NT * 24 + ks) * 64) + q * 16 + (o & 15)) * 8 + jj] = f2bf(v);
  }
  red[t][0] = sa; red[t][1] = ba;
  __syncthreads();
  if (t == 0) {
    float S = 0.f, B = 0.f;
    for (int i = 0; i < 256; ++i) { S += red[i][0]; B += red[i][1]; }
    sb[o] = S; sb[192 + o] = B;
  }
}

__global__ __launch_bounds__(256) void pm_main(
    const float* __restrict__ x, const unsigned short* __restrict__ wg,
    const float* __restrict__ sb, float* __restrict__ out) {
  const int bid = blockIdx.x;       // 2048 blocks = (b, d2, h2)
  const int h2 = bid & 63;
  const int d2 = (bid >> 6) & 15;
  const int b = bid >> 10;
  const int t = threadIdx.x;
  const int lane = t & 63, wv = t >> 6;
  const int j = lane & 31, s = lane >> 5;  // w-quad index, c-pair select

  __shared__ __align__(16) unsigned short A_lds[64 * 776];  // [m=w2][k' padded to 776]
  __shared__ float part[4][2][64][2];
  __shared__ float stats[64][2];   // (rs, mu*rs) per m

  const float* xb = x + (size_t)b * (96 * 32 * 128 * 128);
  const int dbase = 2 * d2, hbase = 2 * h2;

  // ---------- staging: gather -> bf16 LDS, fold in LN partial sums ----------
  float sum0 = 0.f, sq0 = 0.f, sum1 = 0.f, sq1 = 0.f;  // m = 2j and 2j+1
#pragma unroll 4
  for (int u = wv; u < 96; u += 4) {   // unit = (dh 0..3, cq 0..23)
    int dh = u / 24;
    int cq = u - dh * 24;
    int dd = dh >> 1, hh = dh & 1;
    int r0 = cq * 4 + 2 * s;           // channel row pair (r0, r0+1)
    const float* p = xb + ((size_t)(r0 * 32 + dbase + dd) * 128 + (hbase + hh)) * 128 + 4 * j;
    float4 f0 = *(const float4*)p;                  // row r0,  w = 4j..4j+3
    float4 f1 = *(const float4*)(p + 32 * 128 * 128);  // row r0+1
    sum0 += (f0.x + f0.y) + (f1.x + f1.y);
    sq0  += f0.x * f0.x + f0.y * f0.y + f1.x * f1.x + f1.y * f1.y;
    sum1 += (f0.z + f0.w) + (f1.z + f1.w);
    sq1  += f0.z * f0.z + f0.w * f0.w + f1.z * f1.z + f1.w * f1.w;
    int k0 = dh * 192 + cq * 8 + 4 * s;   // k' base: (dh, c=r0, ww=0)
    ushort4 v0 = make_ushort4(f2bf(f0.x), f2bf(f0.y), f2bf(f1.x), f2bf(f1.y));
    ushort4 v1 = make_ushort4(f2bf(f0.z), f2bf(f0.w), f2bf(f1.z), f2bf(f1.w));
    *(ushort4*)&A_lds[(2 * j) * 776 + k0] = v0;       // m = 2j
    *(ushort4*)&A_lds[(2 * j + 1) * 776 + k0] = v1;   // m = 2j+1
  }
  part[wv][s][2 * j][0] = sum0;
  part[wv][s][2 * j][1] = sq0;
  part[wv][s][2 * j + 1][0] = sum1;
  part[wv][s][2 * j + 1][1] = sq1;
  __syncthreads();
  if (t < 64) {
    float S = 0.f, Q = 0.f;
#pragma unroll
    for (int a0 = 0; a0 < 4; ++a0)
#pragma unroll
      for (int c2 = 0; c2 < 2; ++c2) { S += part[a0][c2][t][0]; Q += part[a0][c2][t][1]; }
    float mu = S * (1.f / 768.f);
    float var = Q * (1.f / 768.f) - mu * mu;
    float rs = rsqrtf(var + LN_EPS);
    stats[t][0] = rs;
    stats[t][1] = mu * rs;
  }
  __syncthreads();

  // ---------- GEMM: 64(m) x 192(n) x 768(k), wave wv owns n = wv*48..+47 ----------
  const int al = lane & 15, ah = lane >> 4;
  f32x4 acc[4][3];
#pragma unroll
  for (int mt = 0; mt < 4; ++mt)
#pragma unroll
    for (int nt = 0; nt < 3; ++nt) acc[mt][nt] = {0.f, 0.f, 0.f, 0.f};

  const short8* wgs = (const short8*)wg;
#pragma unroll 2
  for (int ks = 0; ks < 24; ++ks) {
    short8 afr[4];
#pragma unroll
    for (int mt = 0; mt < 4; ++mt)
      afr[mt] = *(const short8*)&A_lds[(mt * 16 + al) * 776 + ks * 32 + ah * 8];
#pragma unroll
    for (int nt = 0; nt < 3; ++nt) {
      short8 bfr = wgs[((wv * 3 + nt) * 24 + ks) * 64 + lane];
#pragma unroll
      for (int mt = 0; mt < 4; ++mt)
        acc[mt][nt] = __builtin_amdgcn_mfma_f32_16x16x32_bf16(afr[mt], bfr, acc[mt][nt], 0, 0, 0);
    }
  }

  // ---------- epilogue: y = rs*acc - (mu*rs)*S[o] + bias[o] ----------
#pragma unroll
  for (int nt = 0; nt < 3; ++nt) {
    int o = wv * 48 + nt * 16 + al;
    float Sv = sb[o], Bv = sb[192 + o];
    float* ob = out + (((size_t)(b * 192 + o) * 16 + d2) * 64 + h2) * 64;
#pragma unroll
    for (int mt = 0; mt < 4; ++mt) {
      int m0 = mt * 16 + ah * 4;
      float4 y;
      y.x = stats[m0 + 0][0] * acc[mt][nt][0] - stats[m0 + 0][1] * Sv + Bv;
      y.y = stats[m0 + 1][0] * acc[mt][nt][1] - stats[m0 + 1][1] * Sv + Bv;
      y.z = stats[m0 + 2][0] * acc[mt][nt][2] - stats[m0 + 2][1] * Sv + Bv;
      y.w = stats[m0 + 3][0] * acc[mt][nt][3] - stats[m0 + 3][1] * Sv + Bv;
      *(float4*)(ob + m0) = y;
    }
  }
}

extern "C" void kernel_launch(void* const* d_in, const int* in_sizes, int n_in,
                              void* d_out, int out_size, void* d_ws, size_t ws_size,
                              hipStream_t stream) {
  (void)in_sizes; (void)n_in; (void)out_size; (void)ws_size;
  const float* x  = (const float*)d_in[0];
  const float* w  = (const float*)d_in[1];
  const float* g  = (const float*)d_in[2];
  const float* be = (const float*)d_in[3];
  unsigned short* wg = (unsigned short*)d_ws;                          // 192*768 bf16 = 589824 B
  float* sb = (float*)((char*)d_ws + 192 * 768 * sizeof(unsigned short));  // S[192], bias[192]
  pm_prep<<<192, 256, 0, stream>>>(w, g, be, wg, sb);
  pm_main<<<2048, 256, 0, stream>>>(x, wg, sb, (float*)d_out);
}

// Round 2
// 170.840 us; speedup vs baseline: 1.2175x; 1.2175x over previous
//
#include <hip/hip_runtime.h>
#include <hip/hip_bf16.h>

typedef __attribute__((ext_vector_type(8))) short short8;
typedef __attribute__((ext_vector_type(4))) float f32x4;

#define LN_EPS 1e-5f

__device__ __forceinline__ unsigned short f2bf(float f) {
  union { float f; unsigned u; } v; v.f = f;
  unsigned r = v.u + 0x7FFFu + ((v.u >> 16) & 1u);
  return (unsigned short)(r >> 16);
}

// Swizzled byte address into A tile: row in [0,32), colb in [0,1536) bytes.
// XOR of bits 4..6 by row&7 spreads the k-column across banks (T2-style).
__device__ __forceinline__ int a_addr(int row, int colb) {
  return row * 1536 + (colb ^ ((row & 7) << 4));
}

// x: (2, 96, 32, 128, 128) f32
// w: (192, 768) f32, gamma/beta: (768,) f32
// out: (2, 192, 16, 64, 64) f32
//
// k-permutation: k' = (dd*2+hh)*192 + c*2 + ww   (orig k = (dd*2+hh)*192 + ww*96 + c)
// Weights pre-swizzled to MFMA B-frag order: [NT(12)][ks(24)][lane(64)][8 bf16]

__global__ __launch_bounds__(256) void pm_prep(
    const float* __restrict__ w, const float* __restrict__ g,
    const float* __restrict__ be, unsigned short* __restrict__ wg,
    float* __restrict__ sb) {
  const int o = blockIdx.x;   // 0..191
  const int t = threadIdx.x;  // 0..255
  __shared__ float red[256][2];
  float sa = 0.f, ba = 0.f;
#pragma unroll
  for (int u = 0; u < 3; ++u) {
    int kp = t + 256 * u;             // k' in 0..767
    int dh = kp / 192;
    int rem = kp - dh * 192;
    int c = rem >> 1, ww = rem & 1;
    int k = dh * 192 + ww * 96 + c;   // original k
    float wv = w[o * 768 + k];
    float v = wv * g[k];
    sa += v;
    ba += wv * be[k];
    int NT = o >> 4, ks = kp >> 5, qq = (kp >> 3) & 3, jj = kp & 7;
    wg[(((NT * 24 + ks) * 64) + qq * 16 + (o & 15)) * 8 + jj] = f2bf(v);
  }
  red[t][0] = sa; red[t][1] = ba;
  __syncthreads();
  if (t == 0) {
    float S = 0.f, B = 0.f;
    for (int i = 0; i < 256; ++i) { S += red[i][0]; B += red[i][1]; }
    sb[o] = S; sb[192 + o] = B;
  }
}

__global__ __launch_bounds__(256, 4) void pm_main(
    const float* __restrict__ x, const unsigned short* __restrict__ wg,
    const float* __restrict__ sb, float* __restrict__ out) {
  const int bid = blockIdx.x;       // 4096 blocks = (b, d2, h2, wh)
  const int wh = bid & 1;           // which 32-wide half of W2
  const int h2 = (bid >> 1) & 63;
  const int d2 = (bid >> 7) & 15;
  const int b = bid >> 11;
  const int t = threadIdx.x;
  const int lane = t & 63, wv = t >> 6;
  const int q = lane & 15, sc = lane >> 4;   // w-quad, channel-pair-select

  __shared__ __align__(16) unsigned char A_lds[32 * 1536];  // 48 KB, swizzled
  __shared__ float stats[32][2];   // (rs, mu*rs) per m
  __shared__ float part[4][32][2]; // per-wave LN partials

  const float* xb = x + (size_t)b * (96 * 32 * 128 * 128);
  const int dd = wv >> 1, hh = wv & 1;           // wave wv owns dh = wv
  const int drow = 2 * d2 + dd, hrow = 2 * h2 + hh;

  // ---------- staging: gather -> bf16 LDS (swizzled), fold LN partials ----------
  float sum0 = 0.f, sq0 = 0.f, sum1 = 0.f, sq1 = 0.f;  // m = 2q and 2q+1
#pragma unroll 4
  for (int cg = 0; cg < 12; ++cg) {        // channel octet group
    int r0 = cg * 8 + 2 * sc;              // channel row pair (r0, r0+1)
    const float* p = xb + ((size_t)(r0 * 32 + drow) * 128 + hrow) * 128 + wh * 64 + 4 * q;
    float4 f0 = *(const float4*)p;                      // channel r0, w = 4q..4q+3
    float4 f1 = *(const float4*)(p + 32 * 128 * 128);   // channel r0+1
    sum0 += (f0.x + f0.y) + (f1.x + f1.y);
    sq0  += f0.x * f0.x + f0.y * f0.y + f1.x * f1.x + f1.y * f1.y;
    sum1 += (f0.z + f0.w) + (f1.z + f1.w);
    sq1  += f0.z * f0.z + f0.w * f0.w + f1.z * f1.z + f1.w * f1.w;
    int colb = 2 * (wv * 192 + cg * 16 + 4 * sc);  // byte col of k' base
    ushort4 v0 = make_ushort4(f2bf(f0.x), f2bf(f0.y), f2bf(f1.x), f2bf(f1.y));
    ushort4 v1 = make_ushort4(f2bf(f0.z), f2bf(f0.w), f2bf(f1.z), f2bf(f1.w));
    *(ushort4*)&A_lds[a_addr(2 * q, colb)] = v0;       // m = 2q
    *(ushort4*)&A_lds[a_addr(2 * q + 1, colb)] = v1;   // m = 2q+1
  }
  // reduce over sc (lanes q, q+16, q+32, q+48)
  sum0 += __shfl_xor(sum0, 16); sum0 += __shfl_xor(sum0, 32);
  sq0  += __shfl_xor(sq0, 16);  sq0  += __shfl_xor(sq0, 32);
  sum1 += __shfl_xor(sum1, 16); sum1 += __shfl_xor(sum1, 32);
  sq1  += __shfl_xor(sq1, 16);  sq1  += __shfl_xor(sq1, 32);
  if (sc == 0) {
    part[wv][2 * q][0] = sum0;     part[wv][2 * q][1] = sq0;
    part[wv][2 * q + 1][0] = sum1; part[wv][2 * q + 1][1] = sq1;
  }
  __syncthreads();
  if (t < 32) {
    float S = 0.f, Q = 0.f;
#pragma unroll
    for (int w4 = 0; w4 < 4; ++w4) { S += part[w4][t][0]; Q += part[w4][t][1]; }
    float mu = S * (1.f / 768.f);
    float var = Q * (1.f / 768.f) - mu * mu;
    float rs = rsqrtf(var + LN_EPS);
    stats[t][0] = rs;
    stats[t][1] = mu * rs;
  }
  __syncthreads();

  // ---------- GEMM: 32(m) x 192(n) x 768(k), wave wv owns n = wv*48..+47 ----------
  const int al = lane & 15, ah = lane >> 4;
  f32x4 acc[2][3];
#pragma unroll
  for (int mt = 0; mt < 2; ++mt)
#pragma unroll
    for (int nt = 0; nt < 3; ++nt) acc[mt][nt] = {0.f, 0.f, 0.f, 0.f};

  const short8* wgs = (const short8*)wg;
#pragma unroll 2
  for (int ks = 0; ks < 24; ++ks) {
    short8 afr[2];
#pragma unroll
    for (int mt = 0; mt < 2; ++mt)
      afr[mt] = *(const short8*)&A_lds[a_addr(mt * 16 + al, ks * 64 + ah * 16)];
#pragma unroll
    for (int nt = 0; nt < 3; ++nt) {
      short8 bfr = wgs[((wv * 3 + nt) * 24 + ks) * 64 + lane];
#pragma unroll
      for (int mt = 0; mt < 2; ++mt)
        acc[mt][nt] = __builtin_amdgcn_mfma_f32_16x16x32_bf16(afr[mt], bfr, acc[mt][nt], 0, 0, 0);
    }
  }

  // ---------- epilogue: y = rs*acc - (mu*rs)*S[o] + bias[o] ----------
#pragma unroll
  for (int nt = 0; nt < 3; ++nt) {
    int o = wv * 48 + nt * 16 + al;
    float Sv = sb[o], Bv = sb[192 + o];
    float* ob = out + (((size_t)(b * 192 + o) * 16 + d2) * 64 + h2) * 64 + wh * 32;
#pragma unroll
    for (int mt = 0; mt < 2; ++mt) {
      int m0 = mt * 16 + ah * 4;
      float4 y;
      y.x = stats[m0 + 0][0] * acc[mt][nt][0] - stats[m0 + 0][1] * Sv + Bv;
      y.y = stats[m0 + 1][0] * acc[mt][nt][1] - stats[m0 + 1][1] * Sv + Bv;
      y.z = stats[m0 + 2][0] * acc[mt][nt][2] - stats[m0 + 2][1] * Sv + Bv;
      y.w = stats[m0 + 3][0] * acc[mt][nt][3] - stats[m0 + 3][1] * Sv + Bv;
      *(float4*)(ob + m0) = y;
    }
  }
}

extern "C" void kernel_launch(void* const* d_in, const int* in_sizes, int n_in,
                              void* d_out, int out_size, void* d_ws, size_t ws_size,
                              hipStream_t stream) {
  (void)in_sizes; (void)n_in; (void)out_size; (void)ws_size;
  const float* x  = (const float*)d_in[0];
  const float* w  = (const float*)d_in[1];
  const float* g  = (const float*)d_in[2];
  const float* be = (const float*)d_in[3];
  unsigned short* wg = (unsigned short*)d_ws;                          // 192*768 bf16
  float* sb = (float*)((char*)d_ws + 192 * 768 * sizeof(unsigned short));  // S[192], bias[192]
  pm_prep<<<192, 256, 0, stream>>>(w, g, be, wg, sb);
  pm_main<<<4096, 256, 0, stream>>>(x, wg, sb, (float*)d_out);
}

// Round 3
// 149.857 us; speedup vs baseline: 1.3880x; 1.1400x over previous
//
#include <hip/hip_runtime.h>
#include <hip/hip_bf16.h>

typedef __attribute__((ext_vector_type(8))) short short8;
typedef __attribute__((ext_vector_type(4))) float f32x4;

#define LN_EPS 1e-5f

__device__ __forceinline__ unsigned short f2bf(float f) {
  union { float f; unsigned u; } v; v.f = f;
  unsigned r = v.u + 0x7FFFu + ((v.u >> 16) & 1u);
  return (unsigned short)(r >> 16);
}

// Swizzled byte address into A tile: row in [0,32), colb in [0,1536) bytes.
__device__ __forceinline__ int a_addr(int row, int colb) {
  return row * 1536 + (colb ^ ((row & 7) << 4));
}

// x: (2, 96, 32, 128, 128) f32 ; w: (192, 768) f32 ; out: (2, 192, 16, 64, 64) f32
// k' = (dd*2+hh)*192 + c*2 + ww   (orig k = (dd*2+hh)*192 + ww*96 + c)
// Weights pre-swizzled to MFMA B-frag order: [NT(12)][ks(24)][lane(64)][8 bf16]

__global__ __launch_bounds__(256) void pm_prep(
    const float* __restrict__ w, const float* __restrict__ g,
    const float* __restrict__ be, unsigned short* __restrict__ wg,
    float* __restrict__ sb) {
  const int o = blockIdx.x;
  const int t = threadIdx.x;
  __shared__ float red[256][2];
  float sa = 0.f, ba = 0.f;
#pragma unroll
  for (int u = 0; u < 3; ++u) {
    int kp = t + 256 * u;
    int dh = kp / 192;
    int rem = kp - dh * 192;
    int c = rem >> 1, ww = rem & 1;
    int k = dh * 192 + ww * 96 + c;
    float wv = w[o * 768 + k];
    float v = wv * g[k];
    sa += v;
    ba += wv * be[k];
    int NT = o >> 4, ks = kp >> 5, qq = (kp >> 3) & 3, jj = kp & 7;
    wg[(((NT * 24 + ks) * 64) + qq * 16 + (o & 15)) * 8 + jj] = f2bf(v);
  }
  red[t][0] = sa; red[t][1] = ba;
  __syncthreads();
  for (int s = 128; s > 0; s >>= 1) {
    if (t < s) { red[t][0] += red[t + s][0]; red[t][1] += red[t + s][1]; }
    __syncthreads();
  }
  if (t == 0) { sb[o] = red[0][0]; sb[192 + o] = red[0][1]; }
}

__global__ __launch_bounds__(256, 3) void pm_main(
    const float* __restrict__ x, const unsigned short* __restrict__ wg,
    const float* __restrict__ sb, float* __restrict__ out) {
  const int bid = blockIdx.x;       // 4096 = (b, d2, h2, wh)
  const int wh = bid & 1;
  const int h2 = (bid >> 1) & 63;
  const int d2 = (bid >> 7) & 15;
  const int b = bid >> 11;
  const int t = threadIdx.x;
  const int lane = t & 63, wv = t >> 6;
  const int q = lane & 15, sc = lane >> 4;

  __shared__ __align__(16) unsigned char A_lds[32 * 1536];  // 48 KB swizzled
  __shared__ float part[4][32][2];
  __shared__ float stats[32][2];

  const float* xb = x + (size_t)b * (96 * 32 * 128 * 128);
  const int cp0 = wv * 12 + sc * 3;          // channel-pair base for this lane
  const float* pc[3];
#pragma unroll
  for (int i = 0; i < 3; ++i)
    pc[i] = xb + (size_t)(2 * (cp0 + i)) * 524288 + wh * 64 + 4 * q;

  float sum0 = 0.f, sq0 = 0.f, sum1 = 0.f, sq1 = 0.f;
  float4 xa[3], xc[3];

  auto issue = [&](int p) {
    int off = (2 * d2 + (p >> 1)) * 16384 + (2 * h2 + (p & 1)) * 128;
#pragma unroll
    for (int i = 0; i < 3; ++i) {
      xa[i] = *(const float4*)(pc[i] + off);
      xc[i] = *(const float4*)(pc[i] + 524288 + off);
    }
  };

  auto consume = [&](int p) {
#pragma unroll
    for (int i = 0; i < 3; ++i) {
      float4 f0 = xa[i], f1 = xc[i];
      sum0 += (f0.x + f0.y) + (f1.x + f1.y);
      sq0  += f0.x * f0.x + f0.y * f0.y + f1.x * f1.x + f1.y * f1.y;
      sum1 += (f0.z + f0.w) + (f1.z + f1.w);
      sq1  += f0.z * f0.z + f0.w * f0.w + f1.z * f1.z + f1.w * f1.w;
      int colb = p * 384 + 8 * (cp0 + i);
      *(ushort4*)&A_lds[a_addr(2 * q, colb)] =
          make_ushort4(f2bf(f0.x), f2bf(f0.y), f2bf(f1.x), f2bf(f1.y));
      *(ushort4*)&A_lds[a_addr(2 * q + 1, colb)] =
          make_ushort4(f2bf(f0.z), f2bf(f0.w), f2bf(f1.z), f2bf(f1.w));
    }
  };

  const int al = lane & 15, ah = lane >> 4;
  const short8* wgs = (const short8*)wg;
  f32x4 acc[2][3];
#pragma unroll
  for (int mt = 0; mt < 2; ++mt)
#pragma unroll
    for (int nt = 0; nt < 3; ++nt) acc[mt][nt] = {0.f, 0.f, 0.f, 0.f};

  issue(0);

#pragma unroll
  for (int p = 0; p < 4; ++p) {
    consume(p);
    if (p == 3) {
      // reduce LN partials over sc (lane bits 4,5)
      sum0 += __shfl_xor(sum0, 16); sum0 += __shfl_xor(sum0, 32);
      sq0  += __shfl_xor(sq0, 16);  sq0  += __shfl_xor(sq0, 32);
      sum1 += __shfl_xor(sum1, 16); sum1 += __shfl_xor(sum1, 32);
      sq1  += __shfl_xor(sq1, 16);  sq1  += __shfl_xor(sq1, 32);
      if (sc == 0) {
        part[wv][2 * q][0] = sum0;     part[wv][2 * q][1] = sq0;
        part[wv][2 * q + 1][0] = sum1; part[wv][2 * q + 1][1] = sq1;
      }
    }
    __syncthreads();

    // B-fragments for this phase FIRST (in-order vmcnt: MFMA won't wait on x)
    short8 bfr[6][3];
#pragma unroll
    for (int ksi = 0; ksi < 6; ++ksi)
#pragma unroll
      for (int nt = 0; nt < 3; ++nt)
        bfr[ksi][nt] = wgs[((wv * 3 + nt) * 24 + (p * 6 + ksi)) * 64 + lane];

    if (p < 3) issue(p + 1);  // next phase's x loads ride under the MFMAs

    if (p == 3) {
      // stats, redundantly by all 256 threads (8x identical writes, benign)
      int row = t & 31;
      float S = part[0][row][0] + part[1][row][0] + part[2][row][0] + part[3][row][0];
      float Q = part[0][row][1] + part[1][row][1] + part[2][row][1] + part[3][row][1];
      float mu = S * (1.f / 768.f);
      float var = Q * (1.f / 768.f) - mu * mu;
      float rs = rsqrtf(var + LN_EPS);
      stats[row][0] = rs;
      stats[row][1] = mu * rs;
    }

#pragma unroll
    for (int ksi = 0; ksi < 6; ++ksi) {
      int ks = p * 6 + ksi;
      short8 afr[2];
#pragma unroll
      for (int mt = 0; mt < 2; ++mt)
        afr[mt] = *(const short8*)&A_lds[a_addr(mt * 16 + al, ks * 64 + ah * 16)];
#pragma unroll
      for (int nt = 0; nt < 3; ++nt)
#pragma unroll
        for (int mt = 0; mt < 2; ++mt)
          acc[mt][nt] = __builtin_amdgcn_mfma_f32_16x16x32_bf16(afr[mt], bfr[ksi][nt], acc[mt][nt], 0, 0, 0);
    }
  }
  __syncthreads();

  // epilogue: y = rs*acc - (mu*rs)*S[o] + bias[o]
#pragma unroll
  for (int nt = 0; nt < 3; ++nt) {
    int o = wv * 48 + nt * 16 + al;
    float Sv = sb[o], Bv = sb[192 + o];
    float* ob = out + (((size_t)(b * 192 + o) * 16 + d2) * 64 + h2) * 64 + wh * 32;
#pragma unroll
    for (int mt = 0; mt < 2; ++mt) {
      int m0 = mt * 16 + ah * 4;
      float4 y;
      y.x = stats[m0 + 0][0] * acc[mt][nt][0] - stats[m0 + 0][1] * Sv + Bv;
      y.y = stats[m0 + 1][0] * acc[mt][nt][1] - stats[m0 + 1][1] * Sv + Bv;
      y.z = stats[m0 + 2][0] * acc[mt][nt][2] - stats[m0 + 2][1] * Sv + Bv;
      y.w = stats[m0 + 3][0] * acc[mt][nt][3] - stats[m0 + 3][1] * Sv + Bv;
      *(float4*)(ob + m0) = y;
    }
  }
}

extern "C" void kernel_launch(void* const* d_in, const int* in_sizes, int n_in,
                              void* d_out, int out_size, void* d_ws, size_t ws_size,
                              hipStream_t stream) {
  (void)in_sizes; (void)n_in; (void)out_size; (void)ws_size;
  const float* x  = (const float*)d_in[0];
  const float* w  = (const float*)d_in[1];
  const float* g  = (const float*)d_in[2];
  const float* be = (const float*)d_in[3];
  unsigned short* wg = (unsigned short*)d_ws;
  float* sb = (float*)((char*)d_ws + 192 * 768 * sizeof(unsigned short));
  pm_prep<<<192, 256, 0, stream>>>(w, g, be, wg, sb);
  pm_main<<<4096, 256, 0, stream>>>(x, wg, sb, (float*)d_out);
}